// Round 13
// baseline (4957.964 us; speedup 1.0000x reference)
//
#include <hip/hip_runtime.h>
#include <math.h>

#define GEPS 1e-7f
#define BNEPS 1e-5f
#define NCOPY 32
#define CSTR 1536   // floats per stats copy: s1(256) q1(256) s2(256) q2(256) sh(128) qh(128) pad

typedef unsigned short u16;
typedef unsigned int   u32;

typedef _Float16 f16x8 __attribute__((ext_vector_type(8)));
typedef float    f32x4 __attribute__((ext_vector_type(4)));

__device__ __forceinline__ float h2f(u16 u){
  _Float16 x = __builtin_bit_cast(_Float16, u); return (float)x;
}
__device__ __forceinline__ u16 f2h(float f){
  _Float16 x = (_Float16)f; return __builtin_bit_cast(u16, x);
}

// async global->LDS DMA, 16B per lane; LDS dest must be wave-uniform base + lane*16
typedef __attribute__((address_space(1))) const void* as1p;
typedef __attribute__((address_space(3))) void*       as3p;
__device__ __forceinline__ void dma16(const u16* g, _Float16* l){
  __builtin_amdgcn_global_load_lds((as1p)g, (as3p)l, 16, 0, 0);
}

// ---------------------------------------------------------------- utilities
__global__ __launch_bounds__(256) void k_zero_i(int* __restrict__ p, int n){
  int i = blockIdx.x*256 + threadIdx.x;
  if (i < n) p[i] = 0;
}
__global__ __launch_bounds__(256) void k_zero_f(float* __restrict__ p, int n){
  int i = blockIdx.x*256 + threadIdx.x;
  if (i < n) p[i] = 0.f;
}

// ---------------------------------------------------------------- CSR build (multi-block scan)
__global__ __launch_bounds__(256) void k_hist(const int* __restrict__ dst, int E,
                                              int* __restrict__ cnt){
  int e = blockIdx.x*256 + threadIdx.x;
  if (e < E) atomicAdd(&cnt[dst[e]], 1);
}

__global__ __launch_bounds__(256) void k_blocksum(const int* __restrict__ cnt, int N,
                                                  int* __restrict__ part){
  __shared__ int s[256];
  int t = threadIdx.x, i = blockIdx.x*256 + t;
  s[t] = (i < N) ? cnt[i] : 0;
  __syncthreads();
  for (int off = 128; off > 0; off >>= 1){
    if (t < off) s[t] += s[t + off];
    __syncthreads();
  }
  if (t == 0) part[blockIdx.x] = s[0];
}

__global__ __launch_bounds__(1024) void k_scanpart(int* __restrict__ part, int NB){
  __shared__ int s[1024];
  int t = threadIdx.x;
  int v = (t < NB) ? part[t] : 0;
  s[t] = v;
  __syncthreads();
  for (int off = 1; off < 1024; off <<= 1){
    int u = (t >= off) ? s[t-off] : 0;
    __syncthreads();
    s[t] += u;
    __syncthreads();
  }
  if (t < NB) part[t] = s[t] - v;   // exclusive
}

__global__ __launch_bounds__(256) void k_scanapply(const int* __restrict__ cnt,
    const int* __restrict__ part, int N, int E,
    int* __restrict__ offs, int* __restrict__ cursor){
  __shared__ int s[256];
  int t = threadIdx.x, i = blockIdx.x*256 + t;
  int v = (i < N) ? cnt[i] : 0;
  s[t] = v;
  __syncthreads();
  for (int off = 1; off < 256; off <<= 1){
    int u = (t >= off) ? s[t-off] : 0;
    __syncthreads();
    s[t] += u;
    __syncthreads();
  }
  int ex = part[blockIdx.x] + s[t] - v;
  if (i < N){
    offs[i]   = ex;
    cursor[i] = ex;
    if (i == N-1) offs[N] = ex + v;
  }
}

// packs src (17b) + bond-combination index (7b: a0*12 + a1*2 + a2, < 72)
__global__ __launch_bounds__(256) void k_scatter(const int* __restrict__ src,
    const int* __restrict__ dst, const int* __restrict__ attr, int E,
    int* __restrict__ cursor, int* __restrict__ esort){
  int e = blockIdx.x*256 + threadIdx.x;
  if (e >= E) return;
  int d = dst[e];
  int pos = atomicAdd(&cursor[d], 1);
  int comb = attr[3*(size_t)e]*12 + attr[3*(size_t)e+1]*2 + attr[3*(size_t)e+2];
  esort[pos] = (src[e] & 0x1ffff) | (comb << 17);
}

// ---------------------------------------------------------------- bond combo table:
// comb[l][c][d] = b0[a0][d]+b1[a1][d]+b2[a2][d], c = a0*12+a1*2+a2 (72 combos/layer)
__global__ __launch_bounds__(256) void k_comb(const float* __restrict__ bond_emb,
    float* __restrict__ comb, int total){
  int id = blockIdx.x*256 + threadIdx.x;
  if (id >= total) return;
  int d = id & 127;
  int c = (id >> 7) % 72;
  int l = (id >> 7) / 72;
  int a0 = c/12, a1 = (c/2)%6, a2 = c&1;
  const float* b = bond_emb + (size_t)l*3*6*128;
  comb[id] = b[a0*128 + d] + b[(6 + a1)*128 + d] + b[(12 + a2)*128 + d];
}

// ---------------------------------------------------------------- weight prep: fp32 [L][K][N] -> fp16 [L][N][K]
__global__ __launch_bounds__(256) void k_wtrans(const float* __restrict__ W,
    u16* __restrict__ Wt, int K, int Nout, int total){
  int id = blockIdx.x*256 + threadIdx.x;
  if (id >= total) return;
  int k   = id % K;
  int rem = id / K;
  int n   = rem % Nout;
  int l   = rem / Nout;
  Wt[id] = f2h(W[((size_t)l*K + k)*Nout + n]);
}

// ---------------------------------------------------------------- atom encoder
__global__ __launch_bounds__(256) void k_atom(const int* __restrict__ x,
    const float* __restrict__ emb, float* __restrict__ h, u16* __restrict__ h16, int N){
  int d = threadIdx.x & 127;
  int n = (blockIdx.x << 1) + (threadIdx.x >> 7);
  if (n >= N) return;
  float s = 0.f;
  #pragma unroll
  for (int i = 0; i < 9; ++i){
    int idx = x[(size_t)n*9 + i];
    s += emb[((size_t)i*119 + idx)*128 + d];
  }
  h[(size_t)n*128 + d]   = s;
  h16[(size_t)n*128 + d] = f2h(s);
}

// ---------------------------------------------------------------- stats copy reduce (sh+qh -> final)
__global__ __launch_bounds__(256) void k_redstats(const float* __restrict__ Cl,
                                                  float* __restrict__ out){
  int t = threadIdx.x;   // 256 threads cover sh(128)+qh(128)
  float s = 0.f;
  #pragma unroll
  for (int c = 0; c < NCOPY; ++c) s += Cl[c*CSTR + 1024 + t];
  out[t] = s;
}

// ---------------------------------------------------------------- fused edge pass:
// fp16 h gathers + precomputed bond-combo table (3 loads/iter vs 5), BN+relu inline,
// one-pass softmax, software-pipelined 1 edge ahead. 1 wave/node, 2 channels/thread.
template<bool PRE_BN>
__global__ __launch_bounds__(256)
void k_edge(const u16* __restrict__ h16,
    const int* __restrict__ offs, const int* __restrict__ esort,
    const float* __restrict__ comb,   // [72][128] for this layer
    const float* __restrict__ tptr,
    const float* __restrict__ ssum_, const float* __restrict__ ssq_,  // final (reduced)
    const float* __restrict__ g, const float* __restrict__ b,
    u16* __restrict__ hh, int N, float invN){
  __shared__ float sg[128], sv[128];
  int tid = threadIdx.x;
  if (PRE_BN){
    if (tid < 128){
      float mu  = ssum_[tid]*invN;
      float var = fmaxf(ssq_[tid]*invN - mu*mu, 0.f);
      float rs  = rsqrtf(var + BNEPS);
      float s   = g[tid]*rs;
      sg[tid] = s;
      sv[tid] = b[tid] - mu*s;
    }
    __syncthreads();
  }
  int lane = tid & 63;
  int n = (blockIdx.x << 2) + (tid >> 6);
  if (n >= N) return;
  int c0 = lane << 1;
  float tl = *tptr;
  float sg0=1.f, sv0=0.f, sg1=1.f, sv1=0.f;
  if (PRE_BN){ sg0=sg[c0]; sv0=sv[c0]; sg1=sg[c0+1]; sv1=sv[c0+1]; }

  int s0 = offs[n], s1 = offs[n+1];
  float den0 = 0.f, acc0 = 0.f, den1 = 0.f, acc1 = 0.f;
  if (s0 < s1){
    int se = esort[s0];
    u32 hv = *(const u32*)(h16 + (size_t)(se & 0x1ffff)*128 + c0);
    float2 ev = *(const float2*)(comb + (se >> 17)*128 + c0);
    for (int e = s0; e < s1; ++e){
      u32 hvN = hv; float2 evN = ev;
      if (e + 1 < s1){                 // prefetch next edge's rows
        int seN = esort[e+1];
        hvN = *(const u32*)(h16 + (size_t)(seN & 0x1ffff)*128 + c0);
        evN = *(const float2*)(comb + (seN >> 17)*128 + c0);
      }
      float x0 = h2f((u16)(hv & 0xffff));
      float x1 = h2f((u16)(hv >> 16));
      if (PRE_BN){
        x0 = fmaxf(x0*sg0 + sv0, 0.f);
        x1 = fmaxf(x1*sg1 + sv1, 0.f);
      }
      float m0 = fmaxf(x0 + ev.x, 0.f) + GEPS;
      float m1 = fmaxf(x1 + ev.y, 0.f) + GEPS;
      float p0 = __expf(m0*tl);
      float p1 = __expf(m1*tl);
      den0 += p0; acc0 += p0*m0;
      den1 += p1; acc1 += p1*m1;
      hv = hvN; ev = evN;
    }
  }
  u32 hv = *(const u32*)(h16 + (size_t)n*128 + c0);
  float x0 = h2f((u16)(hv & 0xffff));
  float x1 = h2f((u16)(hv >> 16));
  if (PRE_BN){
    x0 = fmaxf(x0*sg0 + sv0, 0.f);
    x1 = fmaxf(x1*sg1 + sv1, 0.f);
  }
  float r0 = x0 + acc0 / fmaxf(den0, GEPS);
  float r1 = x1 + acc1 / fmaxf(den1, GEPS);
  u32 pk = (u32)f2h(r0) | ((u32)f2h(r1) << 16);
  *((u32*)hh + (size_t)n*64 + lane) = pk;
}

// ---------------------------------------------------------------- MFMA fp16 GEMM v7:
// 64x128 tile (M halved vs R11): LDS 26 KB -> ~6 blocks/CU, six independent barrier
// domains overlap DMA-drain stalls. Frag-linear LDS (0 conflicts), double-buffered,
// one barrier per 32-K tile, global_load_lds width=16 DMA. BN+relu on A-fragment read.
// Each of 4 waves computes 64 rows x 32 cols (acc[4][2]); stats cols are disjoint
// per wave -> quad-shfl + direct spread-copy atomics, no LDS reduce.
template<bool TRANSFORM, bool OUT32>
__global__ __launch_bounds__(256)
void k_gemm(const u16* __restrict__ A, int lda,
            const u16* __restrict__ Wt,     // [Ncols][K] fp16
            const float* __restrict__ bias,
            const float* __restrict__ sIn, const float* __restrict__ qIn, // copy regions (stride CSTR)
            const float* __restrict__ gam, const float* __restrict__ bet,
            const float* __restrict__ resid,
            void* __restrict__ outv, int ldo,
            u16* __restrict__ out16,                                     // fp16 copy (OUT32 only)
            float* __restrict__ sOut, float* __restrict__ qOut,          // copy regions
            int M, int K){
  __shared__ __align__(16) _Float16 As[2][2048];   // 64 rows x 32 k
  __shared__ __align__(16) _Float16 Bs[2][4096];   // 128 cols x 32 k
  __shared__ float sc[256], shv[256];

  int tid = threadIdx.x;
  int lane = tid & 63;
  int wn   = tid >> 6;
  int quad = lane >> 4, ln = lane & 15;
  int mBase = blockIdx.x * 64;
  int cBase = blockIdx.y * 128;

  // A staging: 1 chunk/thread. chunk dc=tid: frag=dc>>6 (0..3), l2=dc&63;
  // row = frag*16 + (l2&15), k-half = (l2>>4)*8; dest = dc*16B (lane-contig -> DMA-legal)
  int fA = tid >> 6, lA = tid & 63;
  int kA = (lA >> 4) << 3;
  int rA = mBase + fA*16 + (lA & 15); if (rA >= M) rA = M - 1;
  const u16* apA = A + (size_t)rA*lda + kA;
  // B staging: 2 chunks/thread
  int dc0 = tid, dc1 = 256 + tid;
  int f0 = dc0 >> 6, l20 = dc0 & 63;
  int f1 = dc1 >> 6, l21 = dc1 & 63;
  int kB0 = (l20 >> 4) << 3, kB1 = (l21 >> 4) << 3;
  const u16* bp0 = Wt + (size_t)(cBase + f0*16 + (l20 & 15))*K + kB0;
  const u16* bp1 = Wt + (size_t)(cBase + f1*16 + (l21 & 15))*K + kB1;

  // issue tile-0 DMA first so it overlaps the stats pre-loop
  dma16(apA, &As[0][dc0*8]);
  dma16(bp0, &Bs[0][dc0*8]);
  dma16(bp1, &Bs[0][dc1*8]);

  if (TRANSFORM){
    float inv = 1.f/(float)M;
    for (int k = tid; k < K; k += 256){
      float s_ = 0.f, q_ = 0.f;
      #pragma unroll
      for (int c = 0; c < NCOPY; ++c){ s_ += sIn[c*CSTR + k]; q_ += qIn[c*CSTR + k]; }
      float mu  = s_*inv;
      float var = fmaxf(q_*inv - mu*mu, 0.f);
      float rs  = rsqrtf(var + BNEPS);
      float sg  = gam[k]*rs;
      sc[k]  = sg;
      shv[k] = bet[k] - mu*sg;
    }
  }

  f32x4 acc[4][2];
  #pragma unroll
  for (int i = 0; i < 4; ++i)
    #pragma unroll
    for (int j = 0; j < 2; ++j)
      acc[i][j] = (f32x4){0.f,0.f,0.f,0.f};

  int kTiles = K >> 5;
  for (int kt = 0; kt < kTiles; ++kt){
    __syncthreads();                     // drains DMA (vmcnt) + sc/shv writes
    int cb = kt & 1, nbuf = cb ^ 1;
    if (kt + 1 < kTiles){                // prefetch next tile via DMA, overlaps MFMA below
      int k1 = (kt + 1) << 5;
      dma16(apA + k1, &As[nbuf][dc0*8]);
      dma16(bp0 + k1, &Bs[nbuf][dc0*8]);
      dma16(bp1 + k1, &Bs[nbuf][dc1*8]);
    }
    f16x8 af[4], bf[2];
    #pragma unroll
    for (int i = 0; i < 4; ++i)
      af[i] = *(const f16x8*)(&As[cb][i*512 + lane*8]);
    if (TRANSFORM){                      // BN+relu on A fragments (read-side, once per element)
      int kb = kt*32 + quad*8;
      f32x4 s0 = *(const f32x4*)(&sc[kb]);
      f32x4 s1 = *(const f32x4*)(&sc[kb+4]);
      f32x4 v0 = *(const f32x4*)(&shv[kb]);
      f32x4 v1 = *(const f32x4*)(&shv[kb+4]);
      #pragma unroll
      for (int i = 0; i < 4; ++i){
        f16x8 a = af[i], o;
        o[0] = (_Float16)fmaxf((float)a[0]*s0[0] + v0[0], 0.f);
        o[1] = (_Float16)fmaxf((float)a[1]*s0[1] + v0[1], 0.f);
        o[2] = (_Float16)fmaxf((float)a[2]*s0[2] + v0[2], 0.f);
        o[3] = (_Float16)fmaxf((float)a[3]*s0[3] + v0[3], 0.f);
        o[4] = (_Float16)fmaxf((float)a[4]*s1[0] + v1[0], 0.f);
        o[5] = (_Float16)fmaxf((float)a[5]*s1[1] + v1[1], 0.f);
        o[6] = (_Float16)fmaxf((float)a[6]*s1[2] + v1[2], 0.f);
        o[7] = (_Float16)fmaxf((float)a[7]*s1[3] + v1[3], 0.f);
        af[i] = o;
      }
    }
    #pragma unroll
    for (int j = 0; j < 2; ++j)
      bf[j] = *(const f16x8*)(&Bs[cb][(2*wn + j)*512 + lane*8]);
    #pragma unroll
    for (int i = 0; i < 4; ++i)
      #pragma unroll
      for (int j = 0; j < 2; ++j)
        acc[i][j] = __builtin_amdgcn_mfma_f32_16x16x32_f16(af[i], bf[j], acc[i][j], 0, 0, 0);
  }

  // epilogue: each wave owns cols cBase + wn*32 .. +32 (disjoint across waves)
  float bv[2];
  #pragma unroll
  for (int j = 0; j < 2; ++j) bv[j] = bias[cBase + (2*wn + j)*16 + ln];
  float ps[2] = {0,0}, pq[2] = {0,0};

  #pragma unroll
  for (int i = 0; i < 4; ++i){
    #pragma unroll
    for (int r = 0; r < 4; ++r){
      int row = mBase + 16*i + quad*4 + r;
      if (row < M){
        size_t base = (size_t)row*ldo;
        #pragma unroll
        for (int j = 0; j < 2; ++j){
          int col = cBase + (2*wn + j)*16 + ln;
          float v = acc[i][j][r] + bv[j];
          if (OUT32){
            float* out = (float*)outv;
            if (resid) v += resid[base + col];
            out[base + col] = v;
            if (out16) out16[base + col] = f2h(v);
            ps[j] += v; pq[j] += v*v;
          } else {
            u16* out = (u16*)outv;
            u16 q = f2h(v);
            out[base + col] = q;
            float vr = h2f(q);
            ps[j] += vr; pq[j] += vr*vr;
          }
        }
      }
    }
  }
  // stats: quad-shfl reduce, direct spread-copy atomics (cols disjoint per wave)
  #pragma unroll
  for (int j = 0; j < 2; ++j){
    float s = ps[j], q = pq[j];
    s += __shfl_xor(s, 16, 64);  q += __shfl_xor(q, 16, 64);
    s += __shfl_xor(s, 32, 64);  q += __shfl_xor(q, 32, 64);
    if (quad == 0){
      int cof = (blockIdx.x & (NCOPY-1))*CSTR + cBase + (2*wn + j)*16 + ln;
      atomicAdd(&sOut[cof], s);
      atomicAdd(&qOut[cof], q);
    }
  }
}

// ---------------------------------------------------------------- pooling
__global__ __launch_bounds__(256) void k_pool(const float* __restrict__ h,
    const float* __restrict__ ssum, const float* __restrict__ ssq,
    const float* __restrict__ g, const float* __restrict__ b,
    const float* __restrict__ predW, const int* __restrict__ batch,
    float* __restrict__ pool, float* __restrict__ cnt, int N){
  int lane = threadIdx.x & 63;
  int n = (blockIdx.x << 2) + (threadIdx.x >> 6);
  if (n >= N) return;
  float inv = 1.f / (float)N;
  float v = 0.f;
  #pragma unroll
  for (int d = lane; d < 128; d += 64){
    float mu  = ssum[d]*inv;
    float var = fmaxf(ssq[d]*inv - mu*mu, 0.f);
    float rs  = rsqrtf(var + BNEPS);
    float bn  = (h[(size_t)n*128 + d] - mu)*(g[d]*rs) + b[d];
    v += bn * predW[d];
  }
  #pragma unroll
  for (int off = 32; off > 0; off >>= 1) v += __shfl_down(v, off, 64);
  if (lane == 0){
    int gi = batch[n];
    atomicAdd(&pool[gi], v);
    atomicAdd(&cnt[gi], 1.f);
  }
}

__global__ __launch_bounds__(256) void k_final(const float* __restrict__ pool,
    const float* __restrict__ cnt, const float* __restrict__ predb,
    float* __restrict__ out, int G){
  int g = blockIdx.x*256 + threadIdx.x;
  if (g < G) out[g] = pool[g] / fmaxf(cnt[g], 1.f) + predb[0];
}

// ---------------------------------------------------------------- launcher
extern "C" void kernel_launch(void* const* d_in, const int* in_sizes, int n_in,
                              void* d_out, int out_size, void* d_ws, size_t ws_size,
                              hipStream_t stream){
  const int*   x        = (const int*)d_in[0];
  const int*   eidx     = (const int*)d_in[1];
  const int*   eattr    = (const int*)d_in[2];
  const int*   batch    = (const int*)d_in[3];
  const float* atom_emb = (const float*)d_in[4];
  const float* bond_emb = (const float*)d_in[5];
  const float* W1 = (const float*)d_in[6];
  const float* b1 = (const float*)d_in[7];
  const float* g1 = (const float*)d_in[8];
  const float* be1= (const float*)d_in[9];
  const float* W2 = (const float*)d_in[10];
  const float* b2 = (const float*)d_in[11];
  const float* g2 = (const float*)d_in[12];
  const float* be2= (const float*)d_in[13];
  const float* W3 = (const float*)d_in[14];
  const float* b3 = (const float*)d_in[15];
  const float* tt = (const float*)d_in[16];
  const float* ng = (const float*)d_in[17];
  const float* nb = (const float*)d_in[18];
  const float* predW = (const float*)d_in[19];
  const float* predb = (const float*)d_in[20];
  float* out = (float*)d_out;

  const int N = in_sizes[3];
  const int E = in_sizes[1] / 2;
  const int L = in_sizes[16];
  const int G = out_size;
  const int D = 128, H = 256;
  const float invN = 1.f / (float)N;

  char* ws = (char*)d_ws;
  size_t off = 0;
  auto carve = [&](size_t bytes)->void*{
    void* p = ws + off;
    off += (bytes + 511) & ~(size_t)511;
    return p;
  };
  // total ~175 MB
  float* h   = (float*)carve((size_t)N*D*4);   // fp32 residual stream
  u16*   y1  = (u16*)  carve((size_t)N*H*2);   // fp16
  u16*   y2  = (u16*)  carve((size_t)N*H*2);   // fp16
  u16*   hh  = y2;   // hh (fp16, N*D) aliases y2; dead before GEMM2 writes y2
  // h16 aliases y1: written by k_atom / gemm3(l), consumed by edge(l+1) before
  // gemm1(l+1) overwrites y1. Stream-ordered safe.
  u16*   h16 = y1;
  u16*   Wt1 = (u16*) carve((size_t)L*H*D*2);  // [L][256][128]
  u16*   Wt2 = (u16*) carve((size_t)L*H*H*2);  // [L][256][256]
  u16*   Wt3 = (u16*) carve((size_t)L*D*H*2);  // [L][128][256]
  int*  offs   = (int*)carve((size_t)(N+1)*4);
  int*  cursor = (int*)carve((size_t)N*4);
  int*  cnt    = (int*)carve((size_t)N*4);
  int*  part   = (int*)carve(1024*4);
  int*  esort  = (int*)carve((size_t)E*4);
  float* comb  = (float*)carve((size_t)L*72*128*4);      // bond combo tables
  float* stats = (float*)carve((size_t)L*NCOPY*CSTR*4);  // 32-copy regions per layer
  float* fstat = (float*)carve((size_t)L*256*4);         // reduced sh/qh per layer
  float* pool = (float*)carve((size_t)G*4);
  float* cntg = (float*)carve((size_t)G*4);

  int NB = (N + 255) / 256;

  // CSR build (once per call, shared by all 20 layers)
  k_zero_i   <<<NB, 256, 0, stream>>>(cnt, N);
  k_hist     <<<(E+255)/256, 256, 0, stream>>>(eidx + E, E, cnt);
  k_blocksum <<<NB, 256, 0, stream>>>(cnt, N, part);
  k_scanpart <<<1, 1024, 0, stream>>>(part, NB);
  k_scanapply<<<NB, 256, 0, stream>>>(cnt, part, N, E, offs, cursor);
  k_scatter  <<<(E+255)/256, 256, 0, stream>>>(eidx, eidx + E, eattr, E, cursor, esort);
  k_atom     <<<(N+1)/2, 256, 0, stream>>>(x, atom_emb, h, h16, N);
  k_zero_f   <<<(L*NCOPY*CSTR+255)/256, 256, 0, stream>>>(stats, L*NCOPY*CSTR);
  k_comb     <<<((L*72*128)+255)/256, 256, 0, stream>>>(bond_emb, comb, L*72*128);

  // weights -> fp16 transposed [Nout][K]
  k_wtrans<<<((L*H*D)+255)/256, 256, 0, stream>>>(W1, Wt1, D, H, L*H*D);
  k_wtrans<<<((L*H*H)+255)/256, 256, 0, stream>>>(W2, Wt2, H, H, L*H*H);
  k_wtrans<<<((L*D*H)+255)/256, 256, 0, stream>>>(W3, Wt3, H, D, L*D*H);

  int mb = (N + 63) / 64;
  int eb = (N + 3) / 4;
  for (int l = 0; l < L; ++l){
    float* Cl = stats + (size_t)l*NCOPY*CSTR;
    const float* combl = comb + (size_t)l*72*128;
    if (l == 0){
      k_edge<false><<<eb, 256, 0, stream>>>(h16, offs, esort, combl, tt + l,
          nullptr, nullptr, nullptr, nullptr, hh, N, invN);
    } else {
      float* fs = fstat + (size_t)(l-1)*256;
      k_edge<true><<<eb, 256, 0, stream>>>(h16, offs, esort, combl, tt + l,
          fs, fs + 128, ng + (size_t)(l-1)*D, nb + (size_t)(l-1)*D,
          hh, N, invN);
    }
    // y1 = hh @ W1 + b1   (stats -> s1/q1 copies); overwrites h16 (already consumed)
    k_gemm<false,false><<<dim3(mb,2), 256, 0, stream>>>(hh, D,
        Wt1 + (size_t)l*H*D, b1 + (size_t)l*H,
        nullptr, nullptr, nullptr, nullptr, nullptr,
        y1, H, nullptr, Cl + 0, Cl + 256, N, D);
    // y2 = relu(bn(y1)) @ W2 + b2   (stats -> s2/q2 copies)
    k_gemm<true,false><<<dim3(mb,2), 256, 0, stream>>>(y1, H,
        Wt2 + (size_t)l*H*H, b2 + (size_t)l*H,
        Cl + 0, Cl + 256, g1 + (size_t)l*H, be1 + (size_t)l*H, nullptr,
        y2, H, nullptr, Cl + 512, Cl + 768, N, H);
    // h = relu(bn(y2)) @ W3 + b3 (+ h residual for l>0); also emits h16 (into y1 space)
    k_gemm<true,true><<<dim3(mb,1), 256, 0, stream>>>(y2, H,
        Wt3 + (size_t)l*D*H, b3 + (size_t)l*D,
        Cl + 512, Cl + 768, g2 + (size_t)l*H, be2 + (size_t)l*H,
        (l ? h : nullptr),
        h, D, h16, Cl + 1024, Cl + 1152, N, H);
    // reduce sh/qh copies -> final (consumed by next k_edge / k_pool)
    k_redstats<<<1, 256, 0, stream>>>(Cl, fstat + (size_t)l*256);
  }

  float* fsL = fstat + (size_t)(L-1)*256;
  k_zero_f<<<(G+255)/256, 256, 0, stream>>>(pool, G);
  k_zero_f<<<(G+255)/256, 256, 0, stream>>>(cntg, G);
  k_pool  <<<(N+3)/4, 256, 0, stream>>>(h, fsL, fsL + 128,
      ng + (size_t)(L-1)*D, nb + (size_t)(L-1)*D, predW, batch, pool, cntg, N);
  k_final <<<(G+255)/256, 256, 0, stream>>>(pool, cntg, predb, out, G);
}

// Round 14
// 4712.517 us; speedup vs baseline: 1.0521x; 1.0521x over previous
//
#include <hip/hip_runtime.h>
#include <math.h>

#define GEPS 1e-7f
#define BNEPS 1e-5f
#define NCOPY 32
#define CSTR 1536   // floats per stats copy: s1(256) q1(256) s2(256) q2(256) sh(128) qh(128) pad

typedef unsigned short u16;
typedef unsigned int   u32;

typedef _Float16 f16x8 __attribute__((ext_vector_type(8)));
typedef float    f32x4 __attribute__((ext_vector_type(4)));

__device__ __forceinline__ float h2f(u16 u){
  _Float16 x = __builtin_bit_cast(_Float16, u); return (float)x;
}
__device__ __forceinline__ u16 f2h(float f){
  _Float16 x = (_Float16)f; return __builtin_bit_cast(u16, x);
}

// async global->LDS DMA, 16B per lane; LDS dest must be wave-uniform base + lane*16
typedef __attribute__((address_space(1))) const void* as1p;
typedef __attribute__((address_space(3))) void*       as3p;
__device__ __forceinline__ void dma16(const u16* g, _Float16* l){
  __builtin_amdgcn_global_load_lds((as1p)g, (as3p)l, 16, 0, 0);
}

// ---------------------------------------------------------------- utilities
__global__ __launch_bounds__(256) void k_zero_i(int* __restrict__ p, int n){
  int i = blockIdx.x*256 + threadIdx.x;
  if (i < n) p[i] = 0;
}
__global__ __launch_bounds__(256) void k_zero_f(float* __restrict__ p, int n){
  int i = blockIdx.x*256 + threadIdx.x;
  if (i < n) p[i] = 0.f;
}

// ---------------------------------------------------------------- CSR build (multi-block scan)
__global__ __launch_bounds__(256) void k_hist(const int* __restrict__ dst, int E,
                                              int* __restrict__ cnt){
  int e = blockIdx.x*256 + threadIdx.x;
  if (e < E) atomicAdd(&cnt[dst[e]], 1);
}

__global__ __launch_bounds__(256) void k_blocksum(const int* __restrict__ cnt, int N,
                                                  int* __restrict__ part){
  __shared__ int s[256];
  int t = threadIdx.x, i = blockIdx.x*256 + t;
  s[t] = (i < N) ? cnt[i] : 0;
  __syncthreads();
  for (int off = 128; off > 0; off >>= 1){
    if (t < off) s[t] += s[t + off];
    __syncthreads();
  }
  if (t == 0) part[blockIdx.x] = s[0];
}

__global__ __launch_bounds__(1024) void k_scanpart(int* __restrict__ part, int NB){
  __shared__ int s[1024];
  int t = threadIdx.x;
  int v = (t < NB) ? part[t] : 0;
  s[t] = v;
  __syncthreads();
  for (int off = 1; off < 1024; off <<= 1){
    int u = (t >= off) ? s[t-off] : 0;
    __syncthreads();
    s[t] += u;
    __syncthreads();
  }
  if (t < NB) part[t] = s[t] - v;   // exclusive
}

__global__ __launch_bounds__(256) void k_scanapply(const int* __restrict__ cnt,
    const int* __restrict__ part, int N, int E,
    int* __restrict__ offs, int* __restrict__ cursor){
  __shared__ int s[256];
  int t = threadIdx.x, i = blockIdx.x*256 + t;
  int v = (i < N) ? cnt[i] : 0;
  s[t] = v;
  __syncthreads();
  for (int off = 1; off < 256; off <<= 1){
    int u = (t >= off) ? s[t-off] : 0;
    __syncthreads();
    s[t] += u;
    __syncthreads();
  }
  int ex = part[blockIdx.x] + s[t] - v;
  if (i < N){
    offs[i]   = ex;
    cursor[i] = ex;
    if (i == N-1) offs[N] = ex + v;
  }
}

// packs src (17b) + bond-combination index (7b: a0*12 + a1*2 + a2, < 72)
__global__ __launch_bounds__(256) void k_scatter(const int* __restrict__ src,
    const int* __restrict__ dst, const int* __restrict__ attr, int E,
    int* __restrict__ cursor, int* __restrict__ esort){
  int e = blockIdx.x*256 + threadIdx.x;
  if (e >= E) return;
  int d = dst[e];
  int pos = atomicAdd(&cursor[d], 1);
  int comb = attr[3*(size_t)e]*12 + attr[3*(size_t)e+1]*2 + attr[3*(size_t)e+2];
  esort[pos] = (src[e] & 0x1ffff) | (comb << 17);
}

// ---------------------------------------------------------------- bond combo table:
// comb[l][c][d] = b0[a0][d]+b1[a1][d]+b2[a2][d], c = a0*12+a1*2+a2 (72 combos/layer)
__global__ __launch_bounds__(256) void k_comb(const float* __restrict__ bond_emb,
    float* __restrict__ comb, int total){
  int id = blockIdx.x*256 + threadIdx.x;
  if (id >= total) return;
  int d = id & 127;
  int c = (id >> 7) % 72;
  int l = (id >> 7) / 72;
  int a0 = c/12, a1 = (c/2)%6, a2 = c&1;
  const float* b = bond_emb + (size_t)l*3*6*128;
  comb[id] = b[a0*128 + d] + b[(6 + a1)*128 + d] + b[(12 + a2)*128 + d];
}

// ---------------------------------------------------------------- weight prep: fp32 [L][K][N] -> fp16 [L][N][K]
__global__ __launch_bounds__(256) void k_wtrans(const float* __restrict__ W,
    u16* __restrict__ Wt, int K, int Nout, int total){
  int id = blockIdx.x*256 + threadIdx.x;
  if (id >= total) return;
  int k   = id % K;
  int rem = id / K;
  int n   = rem % Nout;
  int l   = rem / Nout;
  Wt[id] = f2h(W[((size_t)l*K + k)*Nout + n]);
}

// ---------------------------------------------------------------- atom encoder
__global__ __launch_bounds__(256) void k_atom(const int* __restrict__ x,
    const float* __restrict__ emb, float* __restrict__ h, u16* __restrict__ h16, int N){
  int d = threadIdx.x & 127;
  int n = (blockIdx.x << 1) + (threadIdx.x >> 7);
  if (n >= N) return;
  float s = 0.f;
  #pragma unroll
  for (int i = 0; i < 9; ++i){
    int idx = x[(size_t)n*9 + i];
    s += emb[((size_t)i*119 + idx)*128 + d];
  }
  h[(size_t)n*128 + d]   = s;
  h16[(size_t)n*128 + d] = f2h(s);
}

// ---------------------------------------------------------------- stats copy reduce (sh+qh -> final)
__global__ __launch_bounds__(256) void k_redstats(const float* __restrict__ Cl,
                                                  float* __restrict__ out){
  int t = threadIdx.x;   // 256 threads cover sh(128)+qh(128)
  float s = 0.f;
  #pragma unroll
  for (int c = 0; c < NCOPY; ++c) s += Cl[c*CSTR + 1024 + t];
  out[t] = s;
}

// ---------------------------------------------------------------- fused edge pass:
// fp16 h gathers + precomputed bond-combo table (3 loads/iter), BN+relu inline,
// one-pass softmax, software-pipelined 1 edge ahead. 1 wave/node, 2 channels/thread.
template<bool PRE_BN>
__global__ __launch_bounds__(256)
void k_edge(const u16* __restrict__ h16,
    const int* __restrict__ offs, const int* __restrict__ esort,
    const float* __restrict__ comb,   // [72][128] for this layer
    const float* __restrict__ tptr,
    const float* __restrict__ ssum_, const float* __restrict__ ssq_,  // final (reduced)
    const float* __restrict__ g, const float* __restrict__ b,
    u16* __restrict__ hh, int N, float invN){
  __shared__ float sg[128], sv[128];
  int tid = threadIdx.x;
  if (PRE_BN){
    if (tid < 128){
      float mu  = ssum_[tid]*invN;
      float var = fmaxf(ssq_[tid]*invN - mu*mu, 0.f);
      float rs  = rsqrtf(var + BNEPS);
      float s   = g[tid]*rs;
      sg[tid] = s;
      sv[tid] = b[tid] - mu*s;
    }
    __syncthreads();
  }
  int lane = tid & 63;
  int n = (blockIdx.x << 2) + (tid >> 6);
  if (n >= N) return;
  int c0 = lane << 1;
  float tl = *tptr;
  float sg0=1.f, sv0=0.f, sg1=1.f, sv1=0.f;
  if (PRE_BN){ sg0=sg[c0]; sv0=sv[c0]; sg1=sg[c0+1]; sv1=sv[c0+1]; }

  int s0 = offs[n], s1 = offs[n+1];
  float den0 = 0.f, acc0 = 0.f, den1 = 0.f, acc1 = 0.f;
  if (s0 < s1){
    int se = esort[s0];
    u32 hv = *(const u32*)(h16 + (size_t)(se & 0x1ffff)*128 + c0);
    float2 ev = *(const float2*)(comb + (se >> 17)*128 + c0);
    for (int e = s0; e < s1; ++e){
      u32 hvN = hv; float2 evN = ev;
      if (e + 1 < s1){                 // prefetch next edge's rows
        int seN = esort[e+1];
        hvN = *(const u32*)(h16 + (size_t)(seN & 0x1ffff)*128 + c0);
        evN = *(const float2*)(comb + (seN >> 17)*128 + c0);
      }
      float x0 = h2f((u16)(hv & 0xffff));
      float x1 = h2f((u16)(hv >> 16));
      if (PRE_BN){
        x0 = fmaxf(x0*sg0 + sv0, 0.f);
        x1 = fmaxf(x1*sg1 + sv1, 0.f);
      }
      float m0 = fmaxf(x0 + ev.x, 0.f) + GEPS;
      float m1 = fmaxf(x1 + ev.y, 0.f) + GEPS;
      float p0 = __expf(m0*tl);
      float p1 = __expf(m1*tl);
      den0 += p0; acc0 += p0*m0;
      den1 += p1; acc1 += p1*m1;
      hv = hvN; ev = evN;
    }
  }
  u32 hv = *(const u32*)(h16 + (size_t)n*128 + c0);
  float x0 = h2f((u16)(hv & 0xffff));
  float x1 = h2f((u16)(hv >> 16));
  if (PRE_BN){
    x0 = fmaxf(x0*sg0 + sv0, 0.f);
    x1 = fmaxf(x1*sg1 + sv1, 0.f);
  }
  float r0 = x0 + acc0 / fmaxf(den0, GEPS);
  float r1 = x1 + acc1 / fmaxf(den1, GEPS);
  u32 pk = (u32)f2h(r0) | ((u32)f2h(r1) << 16);
  *((u32*)hh + (size_t)n*64 + lane) = pk;
}

// ---------------------------------------------------------------- MFMA fp16 GEMM v6 (R11/R12 state — best measured):
// 128x128 tile, frag-linear LDS (0 conflicts), double-buffered, one barrier per 32-K
// tile, global_load_lds width=16 DMA staging for both operands. BN+relu on A-fragment
// read. OUT32 path optionally emits an fp16 copy (h16) for the next edge pass.
template<bool TRANSFORM, bool OUT32>
__global__ __launch_bounds__(256)
void k_gemm(const u16* __restrict__ A, int lda,
            const u16* __restrict__ Wt,     // [Ncols][K] fp16
            const float* __restrict__ bias,
            const float* __restrict__ sIn, const float* __restrict__ qIn, // copy regions (stride CSTR)
            const float* __restrict__ gam, const float* __restrict__ bet,
            const float* __restrict__ resid,
            void* __restrict__ outv, int ldo,
            u16* __restrict__ out16,                                     // fp16 copy (OUT32 only)
            float* __restrict__ sOut, float* __restrict__ qOut,          // copy regions
            int M, int K){
  __shared__ __align__(16) _Float16 As[2][4096];
  __shared__ __align__(16) _Float16 Bs[2][4096];
  __shared__ float sc[256], shv[256];
  __shared__ float redS[256], redQ[256];

  int tid = threadIdx.x;
  int lane = tid & 63;
  int w    = tid >> 6;
  int wm = w & 1, wn = w >> 1;
  int quad = lane >> 4, ln = lane & 15;
  int mBase = blockIdx.x * 128;
  int cBase = blockIdx.y * 128;

  int dc0 = tid, dc1 = 256 + tid;
  int f0 = dc0 >> 6, l20 = dc0 & 63;
  int f1 = dc1 >> 6, l21 = dc1 & 63;
  int kA0 = (l20 >> 4) << 3, kA1 = (l21 >> 4) << 3;
  int rA0 = mBase + f0*16 + (l20 & 15); if (rA0 >= M) rA0 = M - 1;
  int rA1 = mBase + f1*16 + (l21 & 15); if (rA1 >= M) rA1 = M - 1;
  const u16* apA0 = A + (size_t)rA0*lda + kA0;
  const u16* apA1 = A + (size_t)rA1*lda + kA1;
  const u16* bp0  = Wt + (size_t)(cBase + f0*16 + (l20 & 15))*K + kA0;
  const u16* bp1  = Wt + (size_t)(cBase + f1*16 + (l21 & 15))*K + kA1;

  // issue tile-0 DMA first so it overlaps the stats pre-loop
  dma16(apA0, &As[0][dc0*8]);
  dma16(apA1, &As[0][dc1*8]);
  dma16(bp0,  &Bs[0][dc0*8]);
  dma16(bp1,  &Bs[0][dc1*8]);

  if (TRANSFORM){
    float inv = 1.f/(float)M;
    for (int k = tid; k < K; k += 256){
      float s_ = 0.f, q_ = 0.f;
      #pragma unroll
      for (int c = 0; c < NCOPY; ++c){ s_ += sIn[c*CSTR + k]; q_ += qIn[c*CSTR + k]; }
      float mu  = s_*inv;
      float var = fmaxf(q_*inv - mu*mu, 0.f);
      float rs  = rsqrtf(var + BNEPS);
      float sg  = gam[k]*rs;
      sc[k]  = sg;
      shv[k] = bet[k] - mu*sg;
    }
  }

  f32x4 acc[4][4];
  #pragma unroll
  for (int i = 0; i < 4; ++i)
    #pragma unroll
    for (int j = 0; j < 4; ++j)
      acc[i][j] = (f32x4){0.f,0.f,0.f,0.f};

  int kTiles = K >> 5;
  for (int kt = 0; kt < kTiles; ++kt){
    __syncthreads();                     // drains DMA (vmcnt) + sc/shv writes
    int cb = kt & 1, nbuf = cb ^ 1;
    if (kt + 1 < kTiles){                // prefetch next tile via DMA, overlaps MFMA below
      int k1 = (kt + 1) << 5;
      dma16(apA0 + k1, &As[nbuf][dc0*8]);
      dma16(apA1 + k1, &As[nbuf][dc1*8]);
      dma16(bp0 + k1,  &Bs[nbuf][dc0*8]);
      dma16(bp1 + k1,  &Bs[nbuf][dc1*8]);
    }
    f16x8 af[4], bf[4];
    #pragma unroll
    for (int i = 0; i < 4; ++i)
      af[i] = *(const f16x8*)(&As[cb][(4*wm + i)*512 + lane*8]);
    if (TRANSFORM){                      // BN+relu on A fragments (read-side, once per element)
      int kb = kt*32 + quad*8;
      f32x4 s0 = *(const f32x4*)(&sc[kb]);
      f32x4 s1 = *(const f32x4*)(&sc[kb+4]);
      f32x4 v0 = *(const f32x4*)(&shv[kb]);
      f32x4 v1 = *(const f32x4*)(&shv[kb+4]);
      #pragma unroll
      for (int i = 0; i < 4; ++i){
        f16x8 a = af[i], o;
        o[0] = (_Float16)fmaxf((float)a[0]*s0[0] + v0[0], 0.f);
        o[1] = (_Float16)fmaxf((float)a[1]*s0[1] + v0[1], 0.f);
        o[2] = (_Float16)fmaxf((float)a[2]*s0[2] + v0[2], 0.f);
        o[3] = (_Float16)fmaxf((float)a[3]*s0[3] + v0[3], 0.f);
        o[4] = (_Float16)fmaxf((float)a[4]*s1[0] + v1[0], 0.f);
        o[5] = (_Float16)fmaxf((float)a[5]*s1[1] + v1[1], 0.f);
        o[6] = (_Float16)fmaxf((float)a[6]*s1[2] + v1[2], 0.f);
        o[7] = (_Float16)fmaxf((float)a[7]*s1[3] + v1[3], 0.f);
        af[i] = o;
      }
    }
    #pragma unroll
    for (int j = 0; j < 4; ++j)
      bf[j] = *(const f16x8*)(&Bs[cb][(4*wn + j)*512 + lane*8]);
    #pragma unroll
    for (int i = 0; i < 4; ++i)
      #pragma unroll
      for (int j = 0; j < 4; ++j)
        acc[i][j] = __builtin_amdgcn_mfma_f32_16x16x32_f16(af[i], bf[j], acc[i][j], 0, 0, 0);
  }

  // epilogue
  float bv[4];
  #pragma unroll
  for (int j = 0; j < 4; ++j) bv[j] = bias[cBase + 64*wn + 16*j + ln];
  float ps[4] = {0,0,0,0}, pq[4] = {0,0,0,0};

  #pragma unroll
  for (int i = 0; i < 4; ++i){
    int rbase = mBase + 64*wm + 16*i + quad*4;
    #pragma unroll
    for (int r = 0; r < 4; ++r){
      int row = rbase + r;
      if (row < M){
        #pragma unroll
        for (int j = 0; j < 4; ++j){
          int col = cBase + 64*wn + 16*j + ln;
          size_t off = (size_t)row*ldo + col;
          float v = acc[i][j][r] + bv[j];
          if (OUT32){
            float* out = (float*)outv;
            if (resid) v += resid[off];
            out[off] = v;
            if (out16) out16[off] = f2h(v);
            ps[j] += v; pq[j] += v*v;
          } else {
            u16* out = (u16*)outv;
            u16 q = f2h(v);
            out[off] = q;
            float vr = h2f(q);
            ps[j] += vr; pq[j] += vr*vr;
          }
        }
      }
    }
  }
  // stats: quad-shfl reduce, LDS cross-wave (wm) reduce, spread atomics (copy bx&31)
  #pragma unroll
  for (int j = 0; j < 4; ++j){
    float s = ps[j], q = pq[j];
    s += __shfl_xor(s, 16, 64);  q += __shfl_xor(q, 16, 64);
    s += __shfl_xor(s, 32, 64);  q += __shfl_xor(q, 32, 64);
    if (quad == 0){
      int col = 64*wn + 16*j + ln;
      redS[wm*128 + col] = s;
      redQ[wm*128 + col] = q;
    }
  }
  __syncthreads();
  if (tid < 128){
    float s = redS[tid] + redS[128 + tid];
    float q = redQ[tid] + redQ[128 + tid];
    int cof = (blockIdx.x & (NCOPY-1))*CSTR + cBase + tid;
    atomicAdd(&sOut[cof], s);
    atomicAdd(&qOut[cof], q);
  }
}

// ---------------------------------------------------------------- pooling
__global__ __launch_bounds__(256) void k_pool(const float* __restrict__ h,
    const float* __restrict__ ssum, const float* __restrict__ ssq,
    const float* __restrict__ g, const float* __restrict__ b,
    const float* __restrict__ predW, const int* __restrict__ batch,
    float* __restrict__ pool, float* __restrict__ cnt, int N){
  int lane = threadIdx.x & 63;
  int n = (blockIdx.x << 2) + (threadIdx.x >> 6);
  if (n >= N) return;
  float inv = 1.f / (float)N;
  float v = 0.f;
  #pragma unroll
  for (int d = lane; d < 128; d += 64){
    float mu  = ssum[d]*inv;
    float var = fmaxf(ssq[d]*inv - mu*mu, 0.f);
    float rs  = rsqrtf(var + BNEPS);
    float bn  = (h[(size_t)n*128 + d] - mu)*(g[d]*rs) + b[d];
    v += bn * predW[d];
  }
  #pragma unroll
  for (int off = 32; off > 0; off >>= 1) v += __shfl_down(v, off, 64);
  if (lane == 0){
    int gi = batch[n];
    atomicAdd(&pool[gi], v);
    atomicAdd(&cnt[gi], 1.f);
  }
}

__global__ __launch_bounds__(256) void k_final(const float* __restrict__ pool,
    const float* __restrict__ cnt, const float* __restrict__ predb,
    float* __restrict__ out, int G){
  int g = blockIdx.x*256 + threadIdx.x;
  if (g < G) out[g] = pool[g] / fmaxf(cnt[g], 1.f) + predb[0];
}

// ---------------------------------------------------------------- launcher
extern "C" void kernel_launch(void* const* d_in, const int* in_sizes, int n_in,
                              void* d_out, int out_size, void* d_ws, size_t ws_size,
                              hipStream_t stream){
  const int*   x        = (const int*)d_in[0];
  const int*   eidx     = (const int*)d_in[1];
  const int*   eattr    = (const int*)d_in[2];
  const int*   batch    = (const int*)d_in[3];
  const float* atom_emb = (const float*)d_in[4];
  const float* bond_emb = (const float*)d_in[5];
  const float* W1 = (const float*)d_in[6];
  const float* b1 = (const float*)d_in[7];
  const float* g1 = (const float*)d_in[8];
  const float* be1= (const float*)d_in[9];
  const float* W2 = (const float*)d_in[10];
  const float* b2 = (const float*)d_in[11];
  const float* g2 = (const float*)d_in[12];
  const float* be2= (const float*)d_in[13];
  const float* W3 = (const float*)d_in[14];
  const float* b3 = (const float*)d_in[15];
  const float* tt = (const float*)d_in[16];
  const float* ng = (const float*)d_in[17];
  const float* nb = (const float*)d_in[18];
  const float* predW = (const float*)d_in[19];
  const float* predb = (const float*)d_in[20];
  float* out = (float*)d_out;

  const int N = in_sizes[3];
  const int E = in_sizes[1] / 2;
  const int L = in_sizes[16];
  const int G = out_size;
  const int D = 128, H = 256;
  const float invN = 1.f / (float)N;

  char* ws = (char*)d_ws;
  size_t off = 0;
  auto carve = [&](size_t bytes)->void*{
    void* p = ws + off;
    off += (bytes + 511) & ~(size_t)511;
    return p;
  };
  // total ~176 MB
  float* h   = (float*)carve((size_t)N*D*4);   // fp32 residual stream
  u16*   y1  = (u16*)  carve((size_t)N*H*2);   // fp16
  u16*   y2  = (u16*)  carve((size_t)N*H*2);   // fp16
  u16*   hh  = y2;   // hh (fp16, N*D) aliases y2; dead before GEMM2 writes y2
  // h16 aliases y1: written by k_atom / gemm3(l), consumed by edge(l+1) before
  // gemm1(l+1) overwrites y1. Stream-ordered safe.
  u16*   h16 = y1;
  u16*   Wt1 = (u16*) carve((size_t)L*H*D*2);  // [L][256][128]
  u16*   Wt2 = (u16*) carve((size_t)L*H*H*2);  // [L][256][256]
  u16*   Wt3 = (u16*) carve((size_t)L*D*H*2);  // [L][128][256]
  int*  offs   = (int*)carve((size_t)(N+1)*4);
  int*  cursor = (int*)carve((size_t)N*4);
  int*  cnt    = (int*)carve((size_t)N*4);
  int*  part   = (int*)carve(1024*4);
  int*  esort  = (int*)carve((size_t)E*4);
  float* comb  = (float*)carve((size_t)L*72*128*4);      // bond combo tables
  float* stats = (float*)carve((size_t)L*NCOPY*CSTR*4);  // 32-copy regions per layer
  float* fstat = (float*)carve((size_t)L*256*4);         // reduced sh/qh per layer
  float* pool = (float*)carve((size_t)G*4);
  float* cntg = (float*)carve((size_t)G*4);

  int NB = (N + 255) / 256;

  // CSR build (once per call, shared by all 20 layers)
  k_zero_i   <<<NB, 256, 0, stream>>>(cnt, N);
  k_hist     <<<(E+255)/256, 256, 0, stream>>>(eidx + E, E, cnt);
  k_blocksum <<<NB, 256, 0, stream>>>(cnt, N, part);
  k_scanpart <<<1, 1024, 0, stream>>>(part, NB);
  k_scanapply<<<NB, 256, 0, stream>>>(cnt, part, N, E, offs, cursor);
  k_scatter  <<<(E+255)/256, 256, 0, stream>>>(eidx, eidx + E, eattr, E, cursor, esort);
  k_atom     <<<(N+1)/2, 256, 0, stream>>>(x, atom_emb, h, h16, N);
  k_zero_f   <<<(L*NCOPY*CSTR+255)/256, 256, 0, stream>>>(stats, L*NCOPY*CSTR);
  k_comb     <<<((L*72*128)+255)/256, 256, 0, stream>>>(bond_emb, comb, L*72*128);

  // weights -> fp16 transposed [Nout][K]
  k_wtrans<<<((L*H*D)+255)/256, 256, 0, stream>>>(W1, Wt1, D, H, L*H*D);
  k_wtrans<<<((L*H*H)+255)/256, 256, 0, stream>>>(W2, Wt2, H, H, L*H*H);
  k_wtrans<<<((L*D*H)+255)/256, 256, 0, stream>>>(W3, Wt3, H, D, L*D*H);

  int mb = (N + 127) / 128;
  int eb = (N + 3) / 4;
  for (int l = 0; l < L; ++l){
    float* Cl = stats + (size_t)l*NCOPY*CSTR;
    const float* combl = comb + (size_t)l*72*128;
    if (l == 0){
      k_edge<false><<<eb, 256, 0, stream>>>(h16, offs, esort, combl, tt + l,
          nullptr, nullptr, nullptr, nullptr, hh, N, invN);
    } else {
      float* fs = fstat + (size_t)(l-1)*256;
      k_edge<true><<<eb, 256, 0, stream>>>(h16, offs, esort, combl, tt + l,
          fs, fs + 128, ng + (size_t)(l-1)*D, nb + (size_t)(l-1)*D,
          hh, N, invN);
    }
    // y1 = hh @ W1 + b1   (stats -> s1/q1 copies); overwrites h16 (already consumed)
    k_gemm<false,false><<<dim3(mb,2), 256, 0, stream>>>(hh, D,
        Wt1 + (size_t)l*H*D, b1 + (size_t)l*H,
        nullptr, nullptr, nullptr, nullptr, nullptr,
        y1, H, nullptr, Cl + 0, Cl + 256, N, D);
    // y2 = relu(bn(y1)) @ W2 + b2   (stats -> s2/q2 copies)
    k_gemm<true,false><<<dim3(mb,2), 256, 0, stream>>>(y1, H,
        Wt2 + (size_t)l*H*H, b2 + (size_t)l*H,
        Cl + 0, Cl + 256, g1 + (size_t)l*H, be1 + (size_t)l*H, nullptr,
        y2, H, nullptr, Cl + 512, Cl + 768, N, H);
    // h = relu(bn(y2)) @ W3 + b3 (+ h residual for l>0); also emits h16 (into y1 space)
    k_gemm<true,true><<<dim3(mb,1), 256, 0, stream>>>(y2, H,
        Wt3 + (size_t)l*D*H, b3 + (size_t)l*D,
        Cl + 512, Cl + 768, g2 + (size_t)l*H, be2 + (size_t)l*H,
        (l ? h : nullptr),
        h, D, h16, Cl + 1024, Cl + 1152, N, H);
    // reduce sh/qh copies -> final (consumed by next k_edge / k_pool)
    k_redstats<<<1, 256, 0, stream>>>(Cl, fstat + (size_t)l*256);
  }

  float* fsL = fstat + (size_t)(L-1)*256;
  k_zero_f<<<(G+255)/256, 256, 0, stream>>>(pool, G);
  k_zero_f<<<(G+255)/256, 256, 0, stream>>>(cntg, G);
  k_pool  <<<(N+3)/4, 256, 0, stream>>>(h, fsL, fsL + 128,
      ng + (size_t)(L-1)*D, nb + (size_t)(L-1)*D, predW, batch, pool, cntg, N);
  k_final <<<(G+255)/256, 256, 0, stream>>>(pool, cntg, predb, out, G);
}